// Round 9
// baseline (253.228 us; speedup 1.0000x reference)
//
#include <hip/hip_runtime.h>

#define BATCH 8
#define SEQ   2048
#define DIM   768
#define HID   512

typedef __attribute__((ext_vector_type(8))) short  short8;
typedef __attribute__((ext_vector_type(4))) float  f32x4;

#define BAR()    asm volatile("s_barrier" ::: "memory")
#define WAITL0() asm volatile("s_waitcnt lgkmcnt(0)" ::: "memory")
#define VMC(n)   asm volatile("s_waitcnt vmcnt(" #n ")" ::: "memory")

__device__ __forceinline__ unsigned short f2bf(float f) {
  union { float f; unsigned u; } x; x.f = f;
  return (unsigned short)((x.u + 0x7FFFu + ((x.u >> 16) & 1u)) >> 16);
}
__device__ __forceinline__ float bf2f(unsigned short u) {
  union { unsigned u; float f; } x; x.u = ((unsigned)u) << 16;
  return x.f;
}
__device__ __forceinline__ void gll16(const void* g, void* l) {
  __builtin_amdgcn_global_load_lds(
      (const __attribute__((address_space(1))) void*)g,
      (__attribute__((address_space(3))) void*)l, 16, 0, 0);
}
// XOR swizzles (involutions; keep bits 0-3 so 16B chunks stay contiguous)
__device__ __forceinline__ int swz2(int o) { return o ^ (((o >> 8) & 7) << 4); }  // 64B rows
__device__ __forceinline__ int swz3(int o) { return o ^ (((o >> 7) & 7) << 4); }  // 128B rows

// ---------------------------------------------------------------------------
// FUSED dispatch: blocks 0-511 = scores (8-phase 256x256 BK=64, proven r5-8);
// blocks 512-767 = gate (8-phase 256x128, proven r7-8). Both independent
// (each depends only on prepack); fusing overlaps gate with the scores tail
// and removes one launch gap. Bodies are verbatim from the proven kernels.
// ---------------------------------------------------------------------------
__global__ __launch_bounds__(512, 2)
void gemm_qk_gate(const unsigned short* __restrict__ qb, const unsigned short* __restrict__ wsl,
                  float* __restrict__ Cf, float* __restrict__ pl,
                  const unsigned short* __restrict__ W1T, const float* __restrict__ bias,
                  const float* __restrict__ W2, float* __restrict__ pg)
{
  __shared__ __align__(16) unsigned char LDS[131072];

  const int tid  = threadIdx.x;
  const int lane = tid & 63, wid = tid >> 6;
  const int wm   = wid >> 2, wn = wid & 3;
  const int lhi  = lane >> 4, llo = lane & 15;

  if (blockIdx.x < 512) {
    // ================= scores: A=qb pitch 1536B, B=kb slots pitch 8192B =====
    constexpr int NITER = 6;  // K=768 -> 12 BK=64 tiles
    int wg = (((int)blockIdx.x & 7) * 64) + ((int)blockIdx.x >> 3);
    const int z  = wg / 64;
    const int r2 = wg % 64;
    const int by = r2 / 8;
    const int bx = r2 % 8;
    const int brow = by * 256, bcol = bx * 256;

    const char* Abase = (const char*)(qb + (size_t)z * SEQ * DIM) + (size_t)brow * 1536;
    const char* Bbase = (const char*)(wsl + (size_t)z * SEQ * 4096 + 2048) + (size_t)bcol * 8192;

    int sr[2], sk[2];
    #pragma unroll
    for (int c = 0; c < 2; ++c) {
      int o = wid * 2048 + c * 1024 + lane * 16;
      int a = swz3(o);
      sr[c] = a >> 7; sk[c] = a & 127;
    }
    auto stA = [&](int buf, int hh, int t) {
      #pragma unroll
      for (int c = 0; c < 2; ++c)
        gll16(Abase + (size_t)(hh * 128 + sr[c]) * 1536 + t * 128 + sk[c],
              LDS + buf * 32768 + hh * 16384 + wid * 2048 + c * 1024);
    };
    auto stB = [&](int buf, int hh, int t) {
      #pragma unroll
      for (int c = 0; c < 2; ++c)
        gll16(Bbase + (size_t)(hh * 128 + sr[c]) * 8192 + t * 128 + sk[c],
              LDS + 65536 + buf * 32768 + hh * 16384 + wid * 2048 + c * 1024);
    };

    f32x4 acc[8][4];
    #pragma unroll
    for (int m = 0; m < 8; ++m)
      #pragma unroll
      for (int n = 0; n < 4; ++n)
        acc[m][n] = (f32x4)(0.0f);

    stA(0, 0, 0); stA(0, 1, 0); stB(0, 0, 0); stB(0, 1, 0);
    stB(1, 0, 1); stB(1, 1, 1);
    VMC(4);
    BAR();

    auto ITER = [&](int i, bool last) {
      #pragma unroll
      for (int kk = 0; kk < 2; ++kk) {
        const int buf = kk;
        short8 aR[4][2], b0R[2][2], b1R[2][2];
        #pragma unroll
        for (int ph = 0; ph < 4; ++ph) {
          const int h  = ph >> 1;
          const int nh = (ph == 1 || ph == 2) ? 1 : 0;
          if (ph == 0 || ph == 2) {
            #pragma unroll
            for (int fm = 0; fm < 4; ++fm)
              #pragma unroll
              for (int kh = 0; kh < 2; ++kh) {
                int o = (wm * 128 + h * 64 + fm * 16 + llo) * 128 + kh * 64 + lhi * 16;
                aR[fm][kh] = *(const short8*)(LDS + buf * 32768 + swz3(o));
              }
          }
          if (ph == 0) {
            #pragma unroll
            for (int fn = 0; fn < 2; ++fn)
              #pragma unroll
              for (int kh = 0; kh < 2; ++kh) {
                int o = (wn * 64 + fn * 16 + llo) * 128 + kh * 64 + lhi * 16;
                b0R[fn][kh] = *(const short8*)(LDS + 65536 + buf * 32768 + swz3(o));
              }
          }
          if (ph == 1) {
            #pragma unroll
            for (int fn = 0; fn < 2; ++fn)
              #pragma unroll
              for (int kh = 0; kh < 2; ++kh) {
                int o = (wn * 64 + 32 + fn * 16 + llo) * 128 + kh * 64 + lhi * 16;
                b1R[fn][kh] = *(const short8*)(LDS + 65536 + buf * 32768 + swz3(o));
              }
          }
          const int P = kk * 4 + ph;
          if      (P == 0) stA(1, 0, 2 * i + 1);
          else if (P == 1) stA(1, 1, 2 * i + 1);
          else if (P == 2) { if (!last) stB(0, 0, 2 * i + 2); }
          else if (P == 3) { if (!last) stB(0, 1, 2 * i + 2); }
          else if (P == 4) { if (!last) stA(0, 0, 2 * i + 2); }
          else if (P == 5) { if (!last) stA(0, 1, 2 * i + 2); }
          else if (P == 6) { if (!last) stB(1, 0, 2 * i + 3); }
          else if (P == 7) { if (!last) stB(1, 1, 2 * i + 3); }
          if (P == 3) { if (last) { VMC(0); } else { VMC(4); } }
          if (P == 7) { if (!last) { VMC(4); } }
          BAR();
          WAITL0();
          __builtin_amdgcn_sched_barrier(0);
          __builtin_amdgcn_s_setprio(1);
          #pragma unroll
          for (int kh = 0; kh < 2; ++kh)
            #pragma unroll
            for (int fm = 0; fm < 4; ++fm)
              #pragma unroll
              for (int fn = 0; fn < 2; ++fn)
                acc[h * 4 + fm][nh * 2 + fn] = __builtin_amdgcn_mfma_f32_16x16x32_bf16(
                    aR[fm][kh], nh ? b1R[fn][kh] : b0R[fn][kh],
                    acc[h * 4 + fm][nh * 2 + fn], 0, 0, 0);
          __builtin_amdgcn_s_setprio(0);
          BAR();
        }
      }
    };

    for (int i = 0; i < NITER - 1; ++i) ITER(i, false);
    ITER(NITER - 1, true);

    const float rs = 0.02209708691207961f;  // 1/sqrt(2048)
    unsigned short* C16 = reinterpret_cast<unsigned short*>(Cf);
    float cs[4] = {0.f, 0.f, 0.f, 0.f};
    #pragma unroll
    for (int FM = 0; FM < 8; ++FM)
      #pragma unroll
      for (int r = 0; r < 4; ++r) {
        size_t R = (size_t)z * SEQ + (brow + wm * 128 + FM * 16 + lhi * 4 + r);
        #pragma unroll
        for (int FN = 0; FN < 4; ++FN) {
          int col = bcol + wn * 64 + FN * 16 + llo;
          unsigned short us = f2bf(acc[FM][FN][r] * rs);
          C16[R * 4096 + col] = us;
          cs[FN] += __expf(bf2f(us));
        }
      }
    float* cp = (float*)LDS;
    #pragma unroll
    for (int FN = 0; FN < 4; ++FN) {
      cs[FN] += __shfl_xor(cs[FN], 16);
      cs[FN] += __shfl_xor(cs[FN], 32);
      if (lhi == 0) cp[wm * 256 + wn * 64 + FN * 16 + llo] = cs[FN];
    }
    __syncthreads();
    if (tid < 256)
      pl[(size_t)by * 16384 + z * 2048 + bcol + tid] = cp[tid] + cp[256 + tid];
  } else {
    // ================= gate: A=vb slots pitch 8192B, B=W1T pitch 1536B ======
    constexpr int NITER = 6;   // K=768 -> 12 BK=64 tiles
    const int lbid = (int)blockIdx.x - 512;
    int wg = ((lbid & 7) * 32) + (lbid >> 3);
    const int by = wg >> 2, bx = wg & 3;
    const int brow = by * 256, bcol = bx * 128;

    const char* Abase = (const char*)(wsl + 2816) + (size_t)brow * 8192;
    const char* Bbase = (const char*)W1T + (size_t)bcol * 1536;

    int srA[2], skA[2];
    #pragma unroll
    for (int c = 0; c < 2; ++c) {
      int o = wid * 2048 + c * 1024 + lane * 16;
      int a = swz3(o);
      srA[c] = a >> 7; skA[c] = a & 127;
    }
    const int o1 = tid * 16;
    const int a1 = swz3(o1);
    const int sr1 = a1 >> 7, sk1 = a1 & 127;

    auto stA = [&](int buf, int hh, int t) {
      #pragma unroll
      for (int c = 0; c < 2; ++c)
        gll16(Abase + (size_t)(hh * 128 + srA[c]) * 8192 + t * 128 + skA[c],
              LDS + buf * 32768 + hh * 16384 + wid * 2048 + c * 1024);
    };
    auto stB = [&](int buf, int hh, int t) {
      gll16(Bbase + (size_t)(hh * 64 + sr1) * 1536 + t * 128 + sk1,
            LDS + 65536 + buf * 16384 + hh * 8192 + wid * 1024);
    };

    f32x4 acc[8][2];
    #pragma unroll
    for (int m = 0; m < 8; ++m)
      #pragma unroll
      for (int n = 0; n < 2; ++n)
        acc[m][n] = (f32x4)(0.0f);

    stA(0, 0, 0); stA(0, 1, 0); stB(0, 0, 0); stB(0, 1, 0);
    stB(1, 0, 1); stB(1, 1, 1);
    VMC(2);
    BAR();

    auto ITER = [&](int i, bool last) {
      #pragma unroll
      for (int kk = 0; kk < 2; ++kk) {
        const int buf = kk;
        short8 aR[4][2], b0R[2], b1R[2];
        #pragma unroll
        for (int ph = 0; ph < 4; ++ph) {
          const int h  = ph >> 1;
          const int nh = (ph == 1 || ph == 2) ? 1 : 0;
          if (ph == 0 || ph == 2) {
            #pragma unroll
            for (int fm = 0; fm < 4; ++fm)
              #pragma unroll
              for (int kh = 0; kh < 2; ++kh) {
                int o = (wm * 128 + h * 64 + fm * 16 + llo) * 128 + kh * 64 + lhi * 16;
                aR[fm][kh] = *(const short8*)(LDS + buf * 32768 + swz3(o));
              }
          }
          if (ph == 0) {
            #pragma unroll
            for (int kh = 0; kh < 2; ++kh) {
              int o = (wn * 32 + llo) * 128 + kh * 64 + lhi * 16;
              b0R[kh] = *(const short8*)(LDS + 65536 + buf * 16384 + swz3(o));
            }
          }
          if (ph == 1) {
            #pragma unroll
            for (int kh = 0; kh < 2; ++kh) {
              int o = (wn * 32 + 16 + llo) * 128 + kh * 64 + lhi * 16;
              b1R[kh] = *(const short8*)(LDS + 65536 + buf * 16384 + swz3(o));
            }
          }
          const int P = kk * 4 + ph;
          if      (P == 0) stA(1, 0, 2 * i + 1);
          else if (P == 1) stA(1, 1, 2 * i + 1);
          else if (P == 2) { if (!last) stB(0, 0, 2 * i + 2); }
          else if (P == 3) { if (!last) stB(0, 1, 2 * i + 2); }
          else if (P == 4) { if (!last) stA(0, 0, 2 * i + 2); }
          else if (P == 5) { if (!last) stA(0, 1, 2 * i + 2); }
          else if (P == 6) { if (!last) stB(1, 0, 2 * i + 3); }
          else if (P == 7) { if (!last) stB(1, 1, 2 * i + 3); }
          if (P == 3) { if (last) { VMC(0); } else { VMC(2); } }
          if (P == 7) { if (!last) { VMC(2); } }
          BAR();
          WAITL0();
          __builtin_amdgcn_sched_barrier(0);
          __builtin_amdgcn_s_setprio(1);
          #pragma unroll
          for (int kh = 0; kh < 2; ++kh)
            #pragma unroll
            for (int fm = 0; fm < 4; ++fm)
              acc[h * 4 + fm][nh] = __builtin_amdgcn_mfma_f32_16x16x32_bf16(
                  aR[fm][kh], nh ? b1R[kh] : b0R[kh], acc[h * 4 + fm][nh], 0, 0, 0);
          __builtin_amdgcn_s_setprio(0);
          BAR();
        }
      }
    };

    for (int i = 0; i < NITER - 1; ++i) ITER(i, false);
    ITER(NITER - 1, true);

    float* gredF = (float*)LDS;   // [256][4]
    float b1v[2], w2v[2];
    #pragma unroll
    for (int FN = 0; FN < 2; ++FN) {
      int colg = bcol + wn * 32 + FN * 16 + llo;
      b1v[FN] = bias[colg]; w2v[FN] = W2[colg];
    }
    #pragma unroll
    for (int FM = 0; FM < 8; ++FM)
      #pragma unroll
      for (int r = 0; r < 4; ++r) {
        float part = tanhf(acc[FM][0][r] + b1v[0]) * w2v[0]
                   + tanhf(acc[FM][1][r] + b1v[1]) * w2v[1];
        part += __shfl_xor(part, 1);
        part += __shfl_xor(part, 2);
        part += __shfl_xor(part, 4);
        part += __shfl_xor(part, 8);
        if (llo == 0) gredF[(wm * 128 + FM * 16 + lhi * 4 + r) * 4 + wn] = part;
      }
    __syncthreads();
    if (tid < 256)
      pg[(size_t)bx * 16384 + brow + tid] =
          gredF[tid * 4 + 0] + gredF[tid * 4 + 1] + gredF[tid * 4 + 2] + gredF[tid * 4 + 3];
  }
}

// ---------------------------------------------------------------------------
// PV GEMM, 4-phase 128x192 BK=64, LDS 80K -> 2 blocks/CU. Proven rounds 7-8.
// ---------------------------------------------------------------------------
__global__ __launch_bounds__(512, 4)
void gemm_pv(const unsigned short* __restrict__ Ap, const unsigned short* __restrict__ Bp,
             const float* __restrict__ qres, float* __restrict__ Cf)
{
  constexpr int NITER = 16;  // K=2048 -> 32 BK=64 tiles
  __shared__ __align__(16) unsigned char LDS[81920];  // A 2x16K @0, B 2x24K @32768

  int wg = ((blockIdx.x & 7) * 64) + ((int)blockIdx.x >> 3);
  const int z  = wg >> 6;
  const int r2 = wg & 63;
  const int by = r2 >> 2, bx = r2 & 3;
  const int brow = by * 128, bcol = bx * 192;

  const int tid  = threadIdx.x;
  const int lane = tid & 63, wid = tid >> 6;
  const int wm   = wid >> 2, wn = wid & 3;
  const int lhi  = lane >> 4, llo = lane & 15;

  const char* Abase = (const char*)(Ap + (size_t)z * SEQ * SEQ) + (size_t)brow * 4096;
  const char* Bbase = (const char*)(Bp + (size_t)z * (size_t)DIM * SEQ) + (size_t)bcol * 4096;

  const int o1 = tid * 16;
  const int a1 = swz3(o1);
  const int sr1 = a1 >> 7, sk1 = a1 & 127;

  auto stA = [&](int buf, int u, int t) {
    gll16(Abase + (size_t)(u * 64 + sr1) * 4096 + t * 128 + sk1,
          LDS + buf * 16384 + u * 8192 + wid * 1024);
  };
  auto stB = [&](int buf, int u, int t) {
    gll16(Bbase + (size_t)(u * 64 + sr1) * 4096 + t * 128 + sk1,
          LDS + 32768 + buf * 24576 + u * 8192 + wid * 1024);
  };

  f32x4 acc[4][3];
  #pragma unroll
  for (int m = 0; m < 4; ++m)
    #pragma unroll
    for (int n = 0; n < 3; ++n)
      acc[m][n] = (f32x4)(0.0f);

  stA(0, 0, 0); stA(0, 1, 0);
  stB(0, 0, 0); stB(0, 1, 0); stB(0, 2, 0);
  stB(1, 0, 1); stB(1, 1, 1); stB(1, 2, 1);
  VMC(3);
  BAR();

  auto ITER = [&](int i, bool last) {
    short8 aR[2][2], bR[3][2];
    #pragma unroll
    for (int ph = 0; ph < 4; ++ph) {
      const int buf = ph >> 1;
      const int h   = ph & 1;
      #pragma unroll
      for (int fm = 0; fm < 2; ++fm)
        #pragma unroll
        for (int kh = 0; kh < 2; ++kh) {
          int o = (wm * 64 + h * 32 + fm * 16 + llo) * 128 + kh * 64 + lhi * 16;
          aR[fm][kh] = *(const short8*)(LDS + buf * 16384 + swz3(o));
        }
      if (h == 0) {
        #pragma unroll
        for (int fn = 0; fn < 3; ++fn)
          #pragma unroll
          for (int kh = 0; kh < 2; ++kh) {
            int o = (wn * 48 + fn * 16 + llo) * 128 + kh * 64 + lhi * 16;
            bR[fn][kh] = *(const short8*)(LDS + 32768 + buf * 24576 + swz3(o));
          }
      }
      if (ph == 0) { stA(1, 0, 2 * i + 1); stA(1, 1, 2 * i + 1); }
      else if (ph == 1) { if (!last) { stB(0, 0, 2*i+2); stB(0, 1, 2*i+2); stB(0, 2, 2*i+2); } }
      else if (ph == 2) { if (!last) { stA(0, 0, 2*i+2); stA(0, 1, 2*i+2); } }
      else              { if (!last) { stB(1, 0, 2*i+3); stB(1, 1, 2*i+3); stB(1, 2, 2*i+3); } }
      if (ph == 1) { if (last) { VMC(0); } else { VMC(3); } }
      if (ph == 3) { if (!last) { VMC(3); } }
      BAR();
      WAITL0();
      __builtin_amdgcn_sched_barrier(0);
      __builtin_amdgcn_s_setprio(1);
      #pragma unroll
      for (int kh = 0; kh < 2; ++kh)
        #pragma unroll
        for (int fm = 0; fm < 2; ++fm)
          #pragma unroll
          for (int fn = 0; fn < 3; ++fn)
            acc[h * 2 + fm][fn] = __builtin_amdgcn_mfma_f32_16x16x32_bf16(
                aR[fm][kh], bR[fn][kh], acc[h * 2 + fm][fn], 0, 0, 0);
      __builtin_amdgcn_s_setprio(0);
      BAR();
    }
  };

  for (int i = 0; i < NITER - 1; ++i) ITER(i, false);
  ITER(NITER - 1, true);

  float* C = Cf + (size_t)z * SEQ * DIM;
  const float* Q = qres + (size_t)z * SEQ * DIM;
  #pragma unroll
  for (int FM = 0; FM < 4; ++FM)
    #pragma unroll
    for (int r = 0; r < 4; ++r) {
      int rowg = brow + wm * 64 + FM * 16 + lhi * 4 + r;
      #pragma unroll
      for (int FN = 0; FN < 3; ++FN) {
        int colg = bcol + wn * 48 + FN * 16 + llo;
        C[(size_t)rowg * DIM + colg] = acc[FM][FN][r] + Q[(size_t)rowg * DIM + colg];
      }
    }
}

// ---------------------------------------------------------------------------
// Fallback PV GEMM (f32 weights + f32 v), single-buffer — only if ws too small.
// ---------------------------------------------------------------------------
__global__ __launch_bounds__(256)
void gemm_slow(const float* __restrict__ Wf, const float* __restrict__ Vf,
               const float* __restrict__ qres, float* __restrict__ Cf)
{
  __shared__ __align__(16) unsigned short AsL[128 * 64];
  __shared__ __align__(16) unsigned short BsL[128 * 32];

  const int tid  = threadIdx.x;
  const int z    = blockIdx.z;
  const int brow = blockIdx.y * 128;
  const int bcol = blockIdx.x * 128;
  const int lane = tid & 63;
  const int wid  = tid >> 6;
  const int wr   = (wid >> 1) * 64;
  const int wc   = (wid & 1) * 64;
  const int lhi  = lane >> 4;
  const int llo  = lane & 15;

  const float* AsrcF = Wf + (size_t)z * SEQ * SEQ + (size_t)brow * SEQ;
  const float* BsrcF = Vf + (size_t)z * SEQ * DIM;

  f32x4 acc[4][4];
  #pragma unroll
  for (int m = 0; m < 4; ++m)
    #pragma unroll
    for (int n = 0; n < 4; ++n)
      acc[m][n] = (f32x4)(0.0f);

  for (int k0 = 0; k0 < SEQ; k0 += 32) {
    #pragma unroll
    for (int i = 0; i < 4; ++i) {
      int ob = wid * 4096 + i * 1024;
      int a  = swz3(ob + lane * 16);
      gll16((const char*)AsrcF + (size_t)(a >> 7) * (SEQ * 4) + (size_t)k0 * 4 + (a & 127),
            (char*)AsL + ob);
    }
    {
      int n4 = (tid & 31) << 2;
      int kb = (tid >> 5) << 2;
      float4 r0 = *(const float4*)(BsrcF + (size_t)(k0 + kb + 0) * DIM + bcol + n4);
      float4 r1 = *(const float4*)(BsrcF + (size_t)(k0 + kb + 1) * DIM + bcol + n4);
      float4 r2 = *(const float4*)(BsrcF + (size_t)(k0 + kb + 2) * DIM + bcol + n4);
      float4 r3 = *(const float4*)(BsrcF + (size_t)(k0 + kb + 3) * DIM + bcol + n4);
      float a0[4] = {r0.x, r0.y, r0.z, r0.w};
      float a1[4] = {r1.x, r1.y, r1.z, r1.w};
      float a2[4] = {r2.x, r2.y, r2.z, r2.w};
      float a3[4] = {r3.x, r3.y, r3.z, r3.w};
      #pragma unroll
      for (int jj = 0; jj < 4; ++jj) {
        unsigned lo = (__float_as_uint(a0[jj]) >> 16) | (__float_as_uint(a1[jj]) & 0xFFFF0000u);
        unsigned hi = (__float_as_uint(a2[jj]) >> 16) | (__float_as_uint(a3[jj]) & 0xFFFF0000u);
        int ol = (n4 + jj) * 64 + kb * 2;
        *(uint2*)((char*)BsL + swz2(ol)) = make_uint2(lo, hi);
      }
    }
    __syncthreads();

    short8 af[4], bfr[4];
    #pragma unroll
    for (int m = 0; m < 4; ++m) {
      int row = wr + m * 16 + llo;
      int a0i = row * 128 + lhi * 32;
      f32x4 x = *(const f32x4*)((const char*)AsL + swz3(a0i));
      f32x4 y = *(const f32x4*)((const char*)AsL + swz3(a0i + 16));
      union { unsigned u[4]; short8 s; } r;
      r.u[0] = (__float_as_uint(x[0]) >> 16) | (__float_as_uint(x[1]) & 0xFFFF0000u);
      r.u[1] = (__float_as_uint(x[2]) >> 16) | (__float_as_uint(x[3]) & 0xFFFF0000u);
      r.u[2] = (__float_as_uint(y[0]) >> 16) | (__float_as_uint(y[1]) & 0xFFFF0000u);
      r.u[3] = (__float_as_uint(y[2]) >> 16) | (__float_as_uint(y[3]) & 0xFFFF0000u);
      af[m] = r.s;
    }
    #pragma unroll
    for (int n = 0; n < 4; ++n) {
      int a = (wc + n * 16 + llo) * 64 + lhi * 16;
      bfr[n] = *(const short8*)((const char*)BsL + swz2(a));
    }
    #pragma unroll
    for (int m = 0; m < 4; ++m)
      #pragma unroll
      for (int n = 0; n < 4; ++n)
        acc[m][n] = __builtin_amdgcn_mfma_f32_16x16x32_bf16(af[m], bfr[n], acc[m][n], 0, 0, 0);
    __syncthreads();
  }

  float* C = Cf + (size_t)z * SEQ * DIM;
  const float* Q = qres + (size_t)z * SEQ * DIM;
  #pragma unroll
  for (int m = 0; m < 4; ++m)
    #pragma unroll
    for (int r = 0; r < 4; ++r) {
      int rowg = brow + wr + m * 16 + lhi * 4 + r;
      #pragma unroll
      for (int n = 0; n < 4; ++n) {
        int colg = bcol + wc + n * 16 + llo;
        C[(size_t)rowg * DIM + colg] = acc[m][n][r] + Q[(size_t)rowg * DIM + colg];
      }
    }
}

// ---------------------------------------------------------------------------
// Fused prepack + W1 transpose (1D grid: 3072 prepack blocks + 96 W1T blocks).
// ---------------------------------------------------------------------------
__global__ __launch_bounds__(256)
void prepack_all(const float* __restrict__ q, const float* __restrict__ k,
                 const float* __restrict__ v, unsigned short* __restrict__ qb,
                 unsigned short* __restrict__ wsl, unsigned short* __restrict__ vT,
                 const float* __restrict__ W1, unsigned short* __restrict__ W1T,
                 int dovT)
{
  __shared__ unsigned short T[64][66];
  const int bid = blockIdx.x;
  if (bid < 3072) {
    const int bx = bid % 12, byy = (bid / 12) % 32, z = bid / 384;
    const int r0 = byy * 64, c0 = bx * 64;
    const size_t mb = (size_t)z * SEQ * DIM;
    const int t16 = threadIdx.x & 15, trw = threadIdx.x >> 4;

    #pragma unroll
    for (int j = 0; j < 4; ++j) {
      int row = j * 16 + trw;
      size_t e = mb + (size_t)(r0 + row) * DIM + c0 + t16 * 4;
      float4 qv = *(const float4*)(q + e);
      float4 kv = *(const float4*)(k + e);
      float4 vv = *(const float4*)(v + e);
      ushort4 qo; qo.x = f2bf(qv.x); qo.y = f2bf(qv.y); qo.z = f2bf(qv.z); qo.w = f2bf(qv.w);
      ushort4 ko; ko.x = f2bf(kv.x); ko.y = f2bf(kv.y); ko.z = f2bf(kv.z); ko.w = f2bf(kv.w);
      ushort4 vo; vo.x = f2bf(vv.x); vo.y = f2bf(vv.y); vo.z = f2bf(vv.z); vo.w = f2bf(vv.w);
      *(ushort4*)(qb + e) = qo;
      size_t so = (size_t)(z * SEQ + r0 + row) * 4096 + 2048 + c0 + t16 * 4;
      *(ushort4*)(wsl + so) = ko;
      *(ushort4*)(wsl + so + DIM) = vo;
      *(unsigned*)&T[row][t16 * 4]     = (unsigned)vo.x | ((unsigned)vo.y << 16);
      *(unsigned*)&T[row][t16 * 4 + 2] = (unsigned)vo.z | ((unsigned)vo.w << 16);
    }
    __syncthreads();
    if (dovT) {
      const int tc = threadIdx.x & 63, tr2 = threadIdx.x >> 6;
      unsigned short* vTm = vT + (size_t)z * DIM * SEQ;
      #pragma unroll
      for (int j = 0; j < 16; ++j) {
        int orow = j * 4 + tr2;
        vTm[(size_t)(c0 + orow) * SEQ + r0 + tc] = T[tc][orow];
      }
    }
  } else {
    // W1 [768x512] -> W1T [512x768]
    const int idx = bid - 3072;
    const int c0 = (idx & 7) * 64, r0 = (idx >> 3) * 64;
    const int tr = threadIdx.x >> 6, tc = threadIdx.x & 63;
    #pragma unroll
    for (int j = 0; j < 16; ++j) {
      int row = j * 4 + tr;
      T[row][tc] = f2bf(W1[(size_t)(r0 + row) * HID + c0 + tc]);
    }
    __syncthreads();
    #pragma unroll
    for (int j = 0; j < 16; ++j) {
      int row = j * 4 + tr;
      W1T[(size_t)(c0 + row) * DIM + r0 + tc] = T[tc][row];
    }
  }
}

// lcol = sum of 8 scores row-block partials; g = b2 + 4 gate col-block partials
__global__ void finalize(const float* __restrict__ pl, const float* __restrict__ pg,
                         const float* __restrict__ b2, float* __restrict__ lcol,
                         float* __restrict__ g)
{
  int i = blockIdx.x * 256 + threadIdx.x;
  float l = 0.f;
  #pragma unroll
  for (int ch = 0; ch < 8; ++ch) l += pl[ch * 16384 + i];
  lcol[i] = l;
  g[i] = b2[0] + pg[i] + pg[16384 + i] + pg[2 * 16384 + i] + pg[3 * 16384 + i];
}

// ---------------------------------------------------------------------------
// Row pass, wave-per-row (proven round 8): no LDS, no __syncthreads.
// ---------------------------------------------------------------------------
__global__ __launch_bounds__(512)
void rowpass2(float* __restrict__ w, const float* __restrict__ lcol,
              const float* __restrict__ gg, unsigned short* __restrict__ wb)
{
  const int wave = threadIdx.x >> 6;
  const int lane = threadIdx.x & 63;
  const size_t row = (size_t)blockIdx.x * 8 + wave;
  const int b = (int)(row >> 11);
  const unsigned short* p = (const unsigned short*)w + row * 4096;
  float* wrow = w + row * 2048;
  unsigned short* wbrow = wb + row * 2048;
  const float* lc = lcol + (b << 11);
  const float* gb = gg + (b << 11);

  float ev[4][8];
  float psum = 0.f;
  #pragma unroll
  for (int j = 0; j < 4; ++j) {
    const int c0 = j * 512 + lane * 8;
    unsigned short xs[8];
    *(ushort4*)&xs[0] = *(const ushort4*)(p + c0);
    *(ushort4*)&xs[4] = *(const ushort4*)(p + c0 + 4);
    float ls[8], gs[8];
    *(float4*)&ls[0] = *(const float4*)(lc + c0);
    *(float4*)&ls[4] = *(const float4*)(lc + c0 + 4);
    *(float4*)&gs[0] = *(const float4*)(gb + c0);
    *(float4*)&gs[4] = *(const float4*)(gb + c0 + 4);
    #pragma unroll
    for (int jj = 0; jj < 8; ++jj) {
      float s = __expf(bf2f(xs[jj])) / ls[jj];
      float t = (s * (1.f - gs[jj]) + gs[jj] * (1.f / 2048.f)) * 0.03608439182435161f;
      float e = __expf(t);
      ev[j][jj] = e;
      psum += e;
    }
  }
  #pragma unroll
  for (int off = 1; off < 64; off <<= 1) psum += __shfl_xor(psum, off);
  const float inv = 1.f / psum;
  #pragma unroll
  for (int j = 0; j < 4; ++j) {
    const int c0 = j * 512 + lane * 8;
    float4 o0, o1;
    o0.x = ev[j][0] * inv; o0.y = ev[j][1] * inv; o0.z = ev[j][2] * inv; o0.w = ev[j][3] * inv;
    o1.x = ev[j][4] * inv; o1.y = ev[j][5] * inv; o1.z = ev[j][6] * inv; o1.w = ev[j][7] * inv;
    *(float4*)(wrow + c0) = o0;
    *(float4*)(wrow + c0 + 4) = o1;
    ushort4 b0, b1v;
    b0.x = f2bf(o0.x); b0.y = f2bf(o0.y); b0.z = f2bf(o0.z); b0.w = f2bf(o0.w);
    b1v.x = f2bf(o1.x); b1v.y = f2bf(o1.y); b1v.z = f2bf(o1.z); b1v.w = f2bf(o1.w);
    *(ushort4*)(wbrow + c0) = b0;
    *(ushort4*)(wbrow + c0 + 4) = b1v;
  }
}

// Fallback rowpass (no wb copy) — only if ws too small.
__global__ __launch_bounds__(256)
void rowpass_slow(float* __restrict__ w, const float* __restrict__ lcol,
                  const float* __restrict__ gg)
{
  const size_t row = blockIdx.x;
  const int b = (int)(row >> 11);
  const unsigned short* p = (const unsigned short*)w + row * 4096;
  float* wrow = w + row * 2048;
  const int c0 = threadIdx.x * 8;
  const float* lc = lcol + (b << 11);
  const float* gb = gg + (b << 11);

  unsigned short xs[8];
  *(ushort4*)&xs[0] = *(const ushort4*)(p + c0);
  *(ushort4*)&xs[4] = *(const ushort4*)(p + c0 + 4);
  float ls[8], gs[8];
  *(float4*)&ls[0] = *(const float4*)(lc + c0);
  *(float4*)&ls[4] = *(const float4*)(lc + c0 + 4);
  *(float4*)&gs[0] = *(const float4*)(gb + c0);
  *(float4*)&gs[4] = *(const float4*)(gb + c0 + 4);

  float e[8];
  float psum = 0.f;
  #pragma unroll
  for (int j = 0; j < 8; ++j) {
    float s = __expf(bf2f(xs[j])) / ls[j];
    float t = (s * (1.f - gs[j]) + gs[j] * (1.f / 2048.f)) * 0.03608439182435161f;
    float evv = __expf(t);
    e[j] = evv;
    psum += evv;
  }
  #pragma unroll
  for (int off = 1; off < 64; off <<= 1) psum += __shfl_xor(psum, off);
  __shared__ float red[4];
  if ((threadIdx.x & 63) == 0) red[threadIdx.x >> 6] = psum;
  __syncthreads();
  float inv = 1.f / (red[0] + red[1] + red[2] + red[3]);
  float4 o0, o1;
  o0.x = e[0] * inv; o0.y = e[1] * inv; o0.z = e[2] * inv; o0.w = e[3] * inv;
  o1.x = e[4] * inv; o1.y = e[5] * inv; o1.z = e[6] * inv; o1.w = e[7] * inv;
  *(float4*)(wrow + c0) = o0;
  *(float4*)(wrow + c0 + 4) = o1;
}

extern "C" void kernel_launch(void* const* d_in, const int* in_sizes, int n_in,
                              void* d_out, int out_size, void* d_ws, size_t ws_size,
                              hipStream_t stream)
{
  (void)in_sizes; (void)n_in; (void)out_size;
  const float* q  = (const float*)d_in[0];
  const float* k  = (const float*)d_in[1];
  const float* v  = (const float*)d_in[2];
  const float* W1 = (const float*)d_in[3];
  const float* b1 = (const float*)d_in[4];
  const float* W2 = (const float*)d_in[5];
  const float* b2 = (const float*)d_in[6];

  float* out0 = (float*)d_out;                       // [B,S,D] f32 (holds qb until PV)
  float* wbuf = out0 + (size_t)BATCH * SEQ * DIM;    // [B,S,S] f32 weights slots
  unsigned short* wsl = (unsigned short*)wbuf;       // slot view (lower: scores, upper: kb/vb)
  unsigned short* qb  = (unsigned short*)out0;

  float* g    = (float*)d_ws;                        // 16384
  float* lcol = g + 16384;                           // 16384
  float* pg   = lcol + 16384;                        // 65536 (4 used)
  float* pl   = pg + 65536;                          // 262144 (8*16384 used)
  unsigned short* W1T = (unsigned short*)(pl + 262144);            // 393216 ushorts
  unsigned short* vT  = (unsigned short*)((char*)d_ws + 2228224);  // 12.58M ushorts
  unsigned short* wb  = vT + (size_t)12582912;                     // 33.55M ushorts
  const bool fast = ws_size >= 94502912ull;

  prepack_all<<<3168, 256, 0, stream>>>(q, k, v, qb, wsl, vT, W1, W1T, fast ? 1 : 0);

  // fused: scores (blocks 0-511) + gate (blocks 512-767)
  gemm_qk_gate<<<768, 512, 0, stream>>>(qb, wsl, wbuf, pl, W1T, b1, W2, pg);

  finalize<<<64, 256, 0, stream>>>(pl, pg, b2, lcol, g);

  if (fast) {
    rowpass2<<<2048, 512, 0, stream>>>(wbuf, lcol, g, wb);
    gemm_pv<<<512, 512, 0, stream>>>(wb, vT, q, out0);
  } else {
    rowpass_slow<<<16384, 256, 0, stream>>>(wbuf, lcol, g);
    gemm_slow<<<dim3(6, 16, 8), 256, 0, stream>>>(wbuf, v, q, out0);
  }
}